// Round 11
// baseline (2691.053 us; speedup 1.0000x reference)
//
#include <hip/hip_runtime.h>

typedef _Float16 f16;
typedef __attribute__((ext_vector_type(4))) _Float16 f16x4;
typedef __attribute__((ext_vector_type(8))) _Float16 f16x8;
typedef __attribute__((ext_vector_type(16))) float f32x16;

#define MT 128           // batch rows per block
#define NBF 4            // batch fragments (MT/32)
#define LDSP 1024        // act LDS row pitch bytes (512 f16 features)
#define WCHUNK 16384     // weight chunk bytes (16 KiB)

// Packed-weight fragment offsets (f16 elements) inside d_ws
#define OFF2 0
#define OFF3 32768
#define OFF4 163840
#define OFF5 425984
#define OFF6 688128
#define OFF7 950272
#define OFF8 1081344
#define OFF9 1114112
#define TOTAL_FRAG_LANES 139776

// 32 rows -> 32 distinct 16B slots: conflict-free b128 column reads (act).
__device__ __forceinline__ uint32_t swz(int row, int colbytes) {
  return (uint32_t)(row * LDSP + (colbytes ^ ((row & 31) << 4)));
}

// weight repack: fp32 [K][N] -> fp16 A-fragment order (DMA-linear chunks).
__global__ void repack_kernel(const float* __restrict__ W2, const float* __restrict__ W3,
                              const float* __restrict__ W4, const float* __restrict__ W5,
                              const float* __restrict__ W6, const float* __restrict__ W7,
                              const float* __restrict__ W8, const float* __restrict__ W9,
                              f16* __restrict__ ws) {
  int gid = blockIdx.x * 256 + threadIdx.x;
  if (gid >= TOTAL_FRAG_LANES) return;
  const float* src; int N, NT; size_t dst; int local;
  if      (gid <   4096) { src = W2; N = 256; NT = 8;  dst = OFF2; local = gid;          }
  else if (gid <  20480) { src = W3; N = 512; NT = 16; dst = OFF3; local = gid -   4096; }
  else if (gid <  53248) { src = W4; N = 512; NT = 16; dst = OFF4; local = gid -  20480; }
  else if (gid <  86016) { src = W5; N = 512; NT = 16; dst = OFF5; local = gid -  53248; }
  else if (gid < 118784) { src = W6; N = 512; NT = 16; dst = OFF6; local = gid -  86016; }
  else if (gid < 135168) { src = W7; N = 256; NT = 8;  dst = OFF7; local = gid - 118784; }
  else if (gid < 139264) { src = W8; N = 128; NT = 4;  dst = OFF8; local = gid - 135168; }
  else                   { src = W9; N = 3;   NT = 1;  dst = OFF9; local = gid - 139264; }
  int lane = local & 63;
  int frag = local >> 6;
  int kf = frag / NT, nf = frag % NT;
  int n  = nf * 32 + (lane & 31);
  int kb = kf * 16 + ((lane >> 5) << 3);
  f16x8 v;
  #pragma unroll
  for (int i = 0; i < 8; ++i) {
    float val = (n < N) ? src[(size_t)(kb + i) * N + n] : 0.0f;
    v[i] = (f16)val;
  }
  *reinterpret_cast<f16x8*>(ws + dst + (size_t)local * 8) = v;
}

// async global->LDS, 16B per lane, wave-uniform LDS base (HW adds lane*16).
__device__ __forceinline__ void gload16(const f16* g, char* l) {
  __builtin_amdgcn_global_load_lds(
      (const __attribute__((address_space(1))) void*)g,
      (__attribute__((address_space(3))) void*)l, 16, 0, 0);
}

// Stage NI*8KiB of frag-packed weights into LDS linearly. 512 threads:
// wave w, issue i covers LDS [i*8192 + w*1024, +1KiB) <- same global bytes.
template<int NI>
__device__ __forceinline__ void stage_chunk(const f16* __restrict__ src, char* dst, int tid) {
  const int lane = tid & 63, wid = tid >> 6;
  #pragma unroll
  for (int i = 0; i < NI; ++i)
    gload16(src + i * 4096 + wid * 512 + lane * 8, dst + i * 8192 + wid * 1024);
}

// One layer, T3-minimal staged pipeline:
//   per 16KiB chunk: { stage(next chunk -> buf^1); ds_read w(from buf)+b(act);
//                      MFMA; s_waitcnt vmcnt(0); s_barrier; }
// Race-safety: stage targets the buffer whose readers finished before the
// PREVIOUS barrier; reads of chunk c follow every wave's vmcnt(0)+barrier for
// its slice of c.  NC is even -> next layer's chunk0 lands in buf0.
template<int KT, int MF, int WMG, int WBG, int CKF, int NI_NEXT>
__device__ __forceinline__ void run_layer(char* act, char* wlds,
                                          const f16* __restrict__ wp,
                                          const f16* __restrict__ wp_next,
                                          const float* __restrict__ bias, int tid) {
  constexpr int NC = KT / CKF;     // chunks (even for all layers)
  constexpr int FM = MF / WMG;     // out-feature frags per wave
  constexpr int FB = NBF / WBG;    // batch frags per wave
  const int lane  = tid & 63;
  const int wid   = tid >> 6;
  const int wm    = wid / WBG;
  const int wb    = wid % WBG;
  const int mlane = lane & 31;
  const int h     = lane >> 5;

  f32x16 acc[FM][FB];
  #pragma unroll
  for (int fm = 0; fm < FM; ++fm) {
    const int mbase = (wm * FM + fm) * 32;
    #pragma unroll
    for (int g = 0; g < 4; ++g) {
      const float4 bb = *reinterpret_cast<const float4*>(&bias[mbase + g * 8 + 4 * h]);
      #pragma unroll
      for (int j = 0; j < 4; ++j)
        #pragma unroll
        for (int fb = 0; fb < FB; ++fb)
          acc[fm][fb][g * 4 + j] = ((const float*)&bb)[j];
    }
  }

  #pragma unroll 1
  for (int c = 0; c < NC; ++c) {
    const int cur = c & 1;
    // ---- stage next chunk (or next layer's chunk 0) into buf^1 ----
    if (c + 1 < NC)       stage_chunk<2>(wp + (size_t)(c + 1) * (WCHUNK / 2), wlds + (cur ^ 1) * WCHUNK, tid);
    else if (NI_NEXT == 2) stage_chunk<2>(wp_next, wlds + (cur ^ 1) * WCHUNK, tid);
    else if (NI_NEXT == 1) stage_chunk<1>(wp_next, wlds + (cur ^ 1) * WCHUNK, tid);
    // ---- compute chunk c from buf[cur] ----
    char* wbuf = wlds + cur * WCHUNK;
    #pragma unroll
    for (int kk = 0; kk < CKF; ++kk) {
      const int kf = c * CKF + kk;
      f16x8 a[FM];
      #pragma unroll
      for (int fm = 0; fm < FM; ++fm)
        a[fm] = *reinterpret_cast<const f16x8*>(wbuf + (kk * MF + wm * FM + fm) * 1024 + lane * 16);
      f16x8 b[FB];
      #pragma unroll
      for (int fb = 0; fb < FB; ++fb)
        b[fb] = *reinterpret_cast<const f16x8*>(
                    act + swz((wb * FB + fb) * 32 + mlane, kf * 32 + h * 16));
      __builtin_amdgcn_s_setprio(1);
      #pragma unroll
      for (int fm = 0; fm < FM; ++fm)
        #pragma unroll
        for (int fb = 0; fb < FB; ++fb)
          acc[fm][fb] = __builtin_amdgcn_mfma_f32_32x32x16_f16(a[fm], b[fb], acc[fm][fb], 0, 0, 0);
      __builtin_amdgcn_s_setprio(0);
    }
    // ---- chunk boundary: my stage landed; all waves done reading buf[cur] ----
    asm volatile("s_waitcnt vmcnt(0)" ::: "memory");
    __builtin_amdgcn_s_barrier();
    asm volatile("" ::: "memory");
  }

  // epilogue: act reads all closed by the final in-loop barrier
  #pragma unroll
  for (int fm = 0; fm < FM; ++fm) {
    const int mbase = (wm * FM + fm) * 32;
    #pragma unroll
    for (int fb = 0; fb < FB; ++fb) {
      const int row = (wb * FB + fb) * 32 + mlane;   // batch row
      #pragma unroll
      for (int g = 0; g < 4; ++g) {
        const int m0 = mbase + g * 8 + 4 * h;
        f16x4 v;
        #pragma unroll
        for (int j = 0; j < 4; ++j)
          v[j] = (f16)fmaxf(acc[fm][fb][g * 4 + j], 0.0f);
        *reinterpret_cast<f16x4*>(act + swz(row, m0 * 2)) = v;
      }
    }
  }
  __syncthreads();   // act writes visible; next-layer chunk0 DMA drained
}

__global__ __launch_bounds__(512, 2)
void mlp_kernel(const float* __restrict__ x,
                const float* __restrict__ W1, const float* __restrict__ b1,
                const f16*   __restrict__ wpk,
                const float* __restrict__ b2, const float* __restrict__ b3,
                const float* __restrict__ b4, const float* __restrict__ b5,
                const float* __restrict__ b6, const float* __restrict__ b7,
                const float* __restrict__ b8, const float* __restrict__ b9,
                float* __restrict__ out) {
  __shared__ __align__(16) char act[MT * LDSP];       // 128 KiB
  __shared__ __align__(16) char wlds[2 * WCHUNK];     // 32 KiB weight ring
  const int row0 = blockIdx.x * MT;
  const int tid  = threadIdx.x;

  // stage L2 chunk 0 at the very top; lands during L1 compute
  stage_chunk<2>(wpk + OFF2, wlds, tid);

  // ---- Layer 1: 2 -> 128, fp32 VALU ----
  {
    const int r  = tid >> 2;
    const int cb = (tid & 3) * 32;
    const float2 xv = reinterpret_cast<const float2*>(x)[row0 + r];
    #pragma unroll
    for (int q = 0; q < 4; ++q) {
      f16x8 v;
      #pragma unroll
      for (int j = 0; j < 8; ++j) {
        int c = cb + q * 8 + j;
        v[j] = (f16)fmaxf(fmaf(xv.y, W1[128 + c], fmaf(xv.x, W1[c], b1[c])), 0.0f);
      }
      *reinterpret_cast<f16x8*>(act + swz(r, cb * 2 + q * 16)) = v;
    }
  }
  __syncthreads();   // act ready + L2 chunk0 DMA drained

  run_layer<8,  8,  8, 1, 2, 2>(act, wlds, wpk + OFF2, wpk + OFF3, b2, tid);  // 128->256
  run_layer<16, 16, 8, 1, 1, 2>(act, wlds, wpk + OFF3, wpk + OFF4, b3, tid);  // 256->512
  for (int rep = 0; rep < 3; ++rep) {   // L4-L6: 512->512, one emitted body
    const float* bias = (rep == 0) ? b4 : (rep == 1) ? b5 : b6;
    const f16* wp = wpk + OFF4 + rep * (OFF5 - OFF4);
    run_layer<32, 16, 8, 1, 1, 2>(act, wlds, wp, wp + (OFF5 - OFF4), bias, tid);
  }
  run_layer<32, 8,  8, 1, 2, 2>(act, wlds, wpk + OFF7, wpk + OFF8, b7, tid);  // 512->256
  run_layer<16, 4,  4, 2, 4, 1>(act, wlds, wpk + OFF8, wpk + OFF9, b8, tid);  // 256->128

  // ---- Layer 9: 128 -> 3 (padded 32), sigmoid; weights in wlds buf0 ----
  const int lane = tid & 63;
  const int wid  = tid >> 6;
  if (wid < 4) {
    const int mlane = lane & 31;
    const int h     = lane >> 5;
    f32x16 acc = (f32x16)0.0f;
    #pragma unroll
    for (int kf = 0; kf < 8; ++kf) {
      f16x8 a = *reinterpret_cast<const f16x8*>(wlds + kf * 1024 + lane * 16);
      f16x8 b = *reinterpret_cast<const f16x8*>(
                    act + swz(wid * 32 + mlane, kf * 32 + h * 16));
      acc = __builtin_amdgcn_mfma_f32_32x32x16_f16(a, b, acc, 0, 0, 0);
    }
    if (h == 0) {
      const size_t orow = (size_t)(row0 + wid * 32 + mlane) * 3;
      #pragma unroll
      for (int r = 0; r < 3; ++r) {
        float v = acc[r] + b9[r];
        out[orow + r] = 1.0f / (1.0f + __expf(-v));
      }
    }
  }
}

extern "C" void kernel_launch(void* const* d_in, const int* in_sizes, int n_in,
                              void* d_out, int out_size, void* d_ws, size_t ws_size,
                              hipStream_t stream) {
  const float* x  = (const float*)d_in[0];
  const float* W1 = (const float*)d_in[1];  const float* b1 = (const float*)d_in[2];
  const float* W2 = (const float*)d_in[3];  const float* b2 = (const float*)d_in[4];
  const float* W3 = (const float*)d_in[5];  const float* b3 = (const float*)d_in[6];
  const float* W4 = (const float*)d_in[7];  const float* b4 = (const float*)d_in[8];
  const float* W5 = (const float*)d_in[9];  const float* b5 = (const float*)d_in[10];
  const float* W6 = (const float*)d_in[11]; const float* b6 = (const float*)d_in[12];
  const float* W7 = (const float*)d_in[13]; const float* b7 = (const float*)d_in[14];
  const float* W8 = (const float*)d_in[15]; const float* b8 = (const float*)d_in[16];
  const float* W9 = (const float*)d_in[17]; const float* b9 = (const float*)d_in[18];
  f16* wpk = (f16*)d_ws;

  repack_kernel<<<(TOTAL_FRAG_LANES + 255) / 256, 256, 0, stream>>>(
      W2, W3, W4, W5, W6, W7, W8, W9, wpk);

  mlp_kernel<<<1048576 / MT, 512, 0, stream>>>(
      x, W1, b1, wpk, b2, b3, b4, b5, b6, b7, b8, b9, (float*)d_out);
}

// Round 12
// 2103.310 us; speedup vs baseline: 1.2794x; 1.2794x over previous
//
#include <hip/hip_runtime.h>

typedef _Float16 f16;
typedef __attribute__((ext_vector_type(4))) _Float16 f16x4;
typedef __attribute__((ext_vector_type(8))) _Float16 f16x8;
typedef __attribute__((ext_vector_type(16))) float f32x16;

#define MT 128           // batch rows per block
#define NBF 4
#define LDSP 1024        // act row pitch bytes (512 f16)
#define RING_B 32768     // 8 waves x 2 slots x 2 KiB

#define OFF2 0
#define OFF3 32768
#define OFF4 163840
#define OFF5 425984
#define OFF6 688128
#define OFF7 950272
#define OFF8 1081344
#define OFF9 1114112
#define TOTAL_FRAG_LANES 139776

__device__ __forceinline__ uint32_t swz(int row, int colbytes) {
  return (uint32_t)(row * LDSP + (colbytes ^ ((row & 31) << 4)));
}

// weight repack: fp32 [K][N] -> fp16 A-fragment order (1 KiB per frag).
__global__ void repack_kernel(const float* __restrict__ W2, const float* __restrict__ W3,
                              const float* __restrict__ W4, const float* __restrict__ W5,
                              const float* __restrict__ W6, const float* __restrict__ W7,
                              const float* __restrict__ W8, const float* __restrict__ W9,
                              f16* __restrict__ ws) {
  int gid = blockIdx.x * 256 + threadIdx.x;
  if (gid >= TOTAL_FRAG_LANES) return;
  const float* src; int N, NT; size_t dst; int local;
  if      (gid <   4096) { src = W2; N = 256; NT = 8;  dst = OFF2; local = gid;          }
  else if (gid <  20480) { src = W3; N = 512; NT = 16; dst = OFF3; local = gid -   4096; }
  else if (gid <  53248) { src = W4; N = 512; NT = 16; dst = OFF4; local = gid -  20480; }
  else if (gid <  86016) { src = W5; N = 512; NT = 16; dst = OFF5; local = gid -  53248; }
  else if (gid < 118784) { src = W6; N = 512; NT = 16; dst = OFF6; local = gid -  86016; }
  else if (gid < 135168) { src = W7; N = 256; NT = 8;  dst = OFF7; local = gid - 118784; }
  else if (gid < 139264) { src = W8; N = 128; NT = 4;  dst = OFF8; local = gid - 135168; }
  else                   { src = W9; N = 3;   NT = 1;  dst = OFF9; local = gid - 139264; }
  int lane = local & 63;
  int frag = local >> 6;
  int kf = frag / NT, nf = frag % NT;
  int n  = nf * 32 + (lane & 31);
  int kb = kf * 16 + ((lane >> 5) << 3);
  f16x8 v;
  #pragma unroll
  for (int i = 0; i < 8; ++i) {
    float val = (n < N) ? src[(size_t)(kb + i) * N + n] : 0.0f;
    v[i] = (f16)val;
  }
  *reinterpret_cast<f16x8*>(ws + dst + (size_t)local * 8) = v;
}

// async global->LDS: per-lane global src, wave-uniform LDS dst (HW adds lane*16)
__device__ __forceinline__ void gload16(const f16* g, char* l) {
  __builtin_amdgcn_global_load_lds(
      (const __attribute__((address_space(1))) void*)g,
      (__attribute__((address_space(3))) void*)l, 16, 0, 0);
}

// SELF-SERVICE stage: this wave DMAs exactly the 2 KiB of step-t weights that
// THIS wave will ds_read later.  Writer==reader => no cross-wave hazard, no
// barrier needed for the ring.  Slot = t&1.
template<int MF>
__device__ __forceinline__ void stage_step(const f16* __restrict__ wp, int t,
                                           char* ringwave, int wid, int lane) {
  constexpr int KPS = 16 / MF;         // kf per step
  char* dst = ringwave + ((t & 1) << 11);
  int g0, g1;
  if constexpr (MF == 16) { g0 = t * 16 + wid * 2;       g1 = g0 + 1; }
  else                    { g0 = (t * KPS) * MF + wid;   g1 = (t * KPS + 1) * MF + wid; }
  gload16(wp + (size_t)g0 * 512 + (size_t)lane * 8, dst);
  gload16(wp + (size_t)g1 * 512 + (size_t)lane * 8, dst + 1024);
}

// Staged layer: barrier-free k-loop.  Per step (8 MFMA/wave):
//   lgkmcnt(0); DMA stage(s+2) -> slot s&1 (just-freed, self-owned);
//   MFMA cluster1; vmcnt(2) [FIFO => stage(s+1) landed, s+2 in flight];
//   ds_read w(s+1)+b(s+1) -> reg dbuf; MFMA cluster2.
// wc0/wc1 carry step-0 weights in across layers (loaded by prev layer's tail).
template<int KT, int MF, int NXT_MF, bool STAGE_NEXT>
__device__ __forceinline__ void run_staged(char* act, char* ring,
    const f16* __restrict__ wp, const f16* __restrict__ wp_next,
    const float* __restrict__ bias, int tid, f16x8& wc0, f16x8& wc1) {
  constexpr int FM = MF / 8, KPS = 16 / MF, NS = (KT * MF) / 16, BN = KPS * 4;
  const int lane = tid & 63, wid = tid >> 6;
  const int mlane = lane & 31, h = lane >> 5;
  char* ringwave = ring + (wid << 12);
  const uint32_t l16 = (uint32_t)lane * 16;

  f32x16 acc[FM][4];
  #pragma unroll
  for (int fm = 0; fm < FM; ++fm) {
    const int mbase = (wid * FM + fm) * 32;
    #pragma unroll
    for (int g = 0; g < 4; ++g) {
      const float4 bb = *reinterpret_cast<const float4*>(&bias[mbase + g * 8 + 4 * h]);
      #pragma unroll
      for (int j = 0; j < 4; ++j)
        #pragma unroll
        for (int fb = 0; fb < 4; ++fb)
          acc[fm][fb][g * 4 + j] = ((const float*)&bb)[j];
    }
  }

  uint32_t rbase[4], rx[4];
  #pragma unroll
  for (int fb = 0; fb < 4; ++fb) {
    int row = fb * 32 + mlane;
    rbase[fb] = (uint32_t)row * LDSP;
    rx[fb] = (uint32_t)((row & 31) << 4);
  }

  f16x8 cw0 = wc0, cw1 = wc1, nw0, nw1;
  f16x8 cb[BN], nb[BN];
  #pragma unroll
  for (int kk = 0; kk < KPS; ++kk)
    #pragma unroll
    for (int fb = 0; fb < 4; ++fb)
      cb[kk * 4 + fb] = *reinterpret_cast<const f16x8*>(
          act + rbase[fb] + ((uint32_t)(kk * 32 + h * 16) ^ rx[fb]));

#define STEP(S, CW0, CW1, CB, NW0, NW1, NB, DOSTAGE, WAIT0, DOREAD)            \
  {                                                                            \
    asm volatile("s_waitcnt lgkmcnt(0)" ::: "memory");                         \
    if constexpr (DOSTAGE) {                                                   \
      if ((S) + 2 < NS) stage_step<MF>(wp, (S) + 2, ringwave, wid, lane);      \
      else stage_step<NXT_MF>(wp_next, (S) + 2 - NS, ringwave, wid, lane);     \
    }                                                                          \
    __builtin_amdgcn_s_setprio(1);                                             \
    _Pragma("unroll")                                                          \
    for (int fb = 0; fb < 4; ++fb)                                             \
      acc[0][fb] = __builtin_amdgcn_mfma_f32_32x32x16_f16(CW0, CB[fb], acc[0][fb], 0, 0, 0); \
    __builtin_amdgcn_s_setprio(0);                                             \
    if constexpr (WAIT0) { asm volatile("s_waitcnt vmcnt(0)" ::: "memory"); }  \
    else                 { asm volatile("s_waitcnt vmcnt(2)" ::: "memory"); }  \
    if constexpr (DOREAD) {                                                    \
      const char* slot = ringwave + ((((S) + 1) & 1) << 11);                   \
      NW0 = *reinterpret_cast<const f16x8*>(slot + l16);                       \
      NW1 = *reinterpret_cast<const f16x8*>(slot + 1024 + l16);                \
      _Pragma("unroll")                                                        \
      for (int kk = 0; kk < KPS; ++kk)                                         \
        _Pragma("unroll")                                                      \
        for (int fb = 0; fb < 4; ++fb)                                         \
          NB[kk * 4 + fb] = *reinterpret_cast<const f16x8*>(                   \
              act + rbase[fb] + ((uint32_t)((((S) + 1) * KPS + kk) * 32 + h * 16) ^ rx[fb])); \
    }                                                                          \
    __builtin_amdgcn_s_setprio(1);                                             \
    _Pragma("unroll")                                                          \
    for (int fb = 0; fb < 4; ++fb)                                             \
      acc[FM - 1][fb] = __builtin_amdgcn_mfma_f32_32x32x16_f16(CW1, CB[BN - 4 + fb], acc[FM - 1][fb], 0, 0, 0); \
    __builtin_amdgcn_s_setprio(0);                                             \
  }

  constexpr int STEADY = STAGE_NEXT ? NS : NS - 2;
  #pragma unroll 1
  for (int s = 0; s < STEADY; s += 2) {
    STEP(s,     cw0, cw1, cb, nw0, nw1, nb, true, false, true)
    STEP(s + 1, nw0, nw1, nb, cw0, cw1, cb, true, false, true)
  }
  if constexpr (!STAGE_NEXT) {
    STEP(NS - 2, cw0, cw1, cb, nw0, nw1, nb, false, true, true)
    STEP(NS - 1, nw0, nw1, nb, cw0, cw1, cb, false, true, false)
  }
#undef STEP
  wc0 = cw0; wc1 = cw1;   // next layer's step-0 weights (read by the tail)

  __syncthreads();   // all waves done reading act (also drains tail DMA)
  #pragma unroll
  for (int fm = 0; fm < FM; ++fm) {
    const int mbase = (wid * FM + fm) * 32;
    #pragma unroll
    for (int fb = 0; fb < 4; ++fb) {
      const int row = fb * 32 + mlane;
      #pragma unroll
      for (int g = 0; g < 4; ++g) {
        const int m0 = mbase + g * 8 + 4 * h;
        f16x4 v;
        #pragma unroll
        for (int j = 0; j < 4; ++j)
          v[j] = (f16)fmaxf(acc[fm][fb][g * 4 + j], 0.0f);
        *reinterpret_cast<f16x4*>(act + swz(row, m0 * 2)) = v;
      }
    }
  }
  __syncthreads();
}

// L8 direct path (R4-style, small layer)
template<int KT, int MF, int WMG, int WBG>
__device__ __forceinline__ void run_direct(char* act, const f16* __restrict__ wp,
                                           const float* __restrict__ bias, int tid) {
  constexpr int FM = MF / WMG, FB = NBF / WBG;
  const int lane = tid & 63, wid = tid >> 6;
  const int wm = wid / WBG, wb = wid % WBG;
  const int mlane = lane & 31, h = lane >> 5;

  f32x16 acc[FM][FB];
  #pragma unroll
  for (int fm = 0; fm < FM; ++fm) {
    const int mbase = (wm * FM + fm) * 32;
    #pragma unroll
    for (int g = 0; g < 4; ++g) {
      const float4 bb = *reinterpret_cast<const float4*>(&bias[mbase + g * 8 + 4 * h]);
      #pragma unroll
      for (int j = 0; j < 4; ++j)
        #pragma unroll
        for (int fb = 0; fb < FB; ++fb)
          acc[fm][fb][g * 4 + j] = ((const float*)&bb)[j];
    }
  }
  const f16x8* __restrict__ wfrag = reinterpret_cast<const f16x8*>(wp);
  #pragma unroll 2
  for (int kf = 0; kf < KT; ++kf) {
    f16x8 a[FM];
    #pragma unroll
    for (int fm = 0; fm < FM; ++fm)
      a[fm] = wfrag[(size_t)(kf * MF + wm * FM + fm) * 64 + lane];
    f16x8 b[FB];
    #pragma unroll
    for (int fb = 0; fb < FB; ++fb)
      b[fb] = *reinterpret_cast<const f16x8*>(
          act + swz((wb * FB + fb) * 32 + mlane, kf * 32 + h * 16));
    #pragma unroll
    for (int fm = 0; fm < FM; ++fm)
      #pragma unroll
      for (int fb = 0; fb < FB; ++fb)
        acc[fm][fb] = __builtin_amdgcn_mfma_f32_32x32x16_f16(a[fm], b[fb], acc[fm][fb], 0, 0, 0);
  }
  __syncthreads();
  #pragma unroll
  for (int fm = 0; fm < FM; ++fm) {
    const int mbase = (wm * FM + fm) * 32;
    #pragma unroll
    for (int fb = 0; fb < FB; ++fb) {
      const int row = (wb * FB + fb) * 32 + mlane;
      #pragma unroll
      for (int g = 0; g < 4; ++g) {
        const int m0 = mbase + g * 8 + 4 * h;
        f16x4 v;
        #pragma unroll
        for (int j = 0; j < 4; ++j)
          v[j] = (f16)fmaxf(acc[fm][fb][g * 4 + j], 0.0f);
        *reinterpret_cast<f16x4*>(act + swz(row, m0 * 2)) = v;
      }
    }
  }
  __syncthreads();
}

__global__ __launch_bounds__(512, 2)
void mlp_kernel(const float* __restrict__ x,
                const float* __restrict__ W1, const float* __restrict__ b1,
                const f16*   __restrict__ wpk,
                const float* __restrict__ b2, const float* __restrict__ b3,
                const float* __restrict__ b4, const float* __restrict__ b5,
                const float* __restrict__ b6, const float* __restrict__ b7,
                const float* __restrict__ b8, const float* __restrict__ b9,
                float* __restrict__ out) {
  __shared__ __align__(16) char act[MT * LDSP];   // 128 KiB
  __shared__ __align__(16) char ring[RING_B];     // 32 KiB: 8 waves x 2 x 2 KiB
  const int row0 = blockIdx.x * MT;
  const int tid  = threadIdx.x;
  const int lane = tid & 63, wid = tid >> 6;
  char* ringwave = ring + (wid << 12);

  // stage L2 steps 0,1 (lands during L1 compute; drained by the syncthreads)
  stage_step<8>(wpk + OFF2, 0, ringwave, wid, lane);
  stage_step<8>(wpk + OFF2, 1, ringwave, wid, lane);

  // ---- Layer 1: 2 -> 128, fp32 VALU ----
  {
    const int r  = tid >> 2;
    const int cb = (tid & 3) * 32;
    const float2 xv = reinterpret_cast<const float2*>(x)[row0 + r];
    #pragma unroll
    for (int q = 0; q < 4; ++q) {
      f16x8 v;
      #pragma unroll
      for (int j = 0; j < 8; ++j) {
        int c = cb + q * 8 + j;
        v[j] = (f16)fmaxf(fmaf(xv.y, W1[128 + c], fmaf(xv.x, W1[c], b1[c])), 0.0f);
      }
      *reinterpret_cast<f16x8*>(act + swz(r, cb * 2 + q * 16)) = v;
    }
  }
  __syncthreads();   // act ready; L2 step0/1 DMA drained

  f16x8 wc0 = *reinterpret_cast<const f16x8*>(ringwave + (uint32_t)lane * 16);
  f16x8 wc1 = *reinterpret_cast<const f16x8*>(ringwave + 1024 + (uint32_t)lane * 16);

  run_staged<8,  8,  16, true >(act, ring, wpk + OFF2, wpk + OFF3, b2, tid, wc0, wc1);
  run_staged<16, 16, 16, true >(act, ring, wpk + OFF3, wpk + OFF4, b3, tid, wc0, wc1);
  #pragma unroll 1
  for (int rep = 0; rep < 2; ++rep)
    run_staged<32, 16, 16, true>(act, ring, wpk + OFF4 + rep * (OFF5 - OFF4),
                                 wpk + OFF5 + rep * (OFF5 - OFF4),
                                 (rep == 0) ? b4 : b5, tid, wc0, wc1);
  run_staged<32, 16, 8,  true >(act, ring, wpk + OFF6, wpk + OFF7, b6, tid, wc0, wc1);
  run_staged<32, 8,  8,  false>(act, ring, wpk + OFF7, wpk,        b7, tid, wc0, wc1);
  run_direct<16, 4, 4, 2>(act, wpk + OFF8, b8, tid);

  // ---- Layer 9: 128 -> 3 (padded 32), sigmoid ----
  if (wid < 4) {
    const int mlane = lane & 31;
    const int h     = lane >> 5;
    f32x16 acc = (f32x16)0.0f;
    const f16x8* __restrict__ wfrag = reinterpret_cast<const f16x8*>(wpk + OFF9);
    #pragma unroll
    for (int kf = 0; kf < 8; ++kf) {
      f16x8 a = wfrag[(size_t)kf * 64 + lane];
      f16x8 b = *reinterpret_cast<const f16x8*>(
          act + swz(wid * 32 + mlane, kf * 32 + h * 16));
      acc = __builtin_amdgcn_mfma_f32_32x32x16_f16(a, b, acc, 0, 0, 0);
    }
    if (h == 0) {
      const size_t orow = (size_t)(row0 + wid * 32 + mlane) * 3;
      #pragma unroll
      for (int r = 0; r < 3; ++r) {
        float v = acc[r] + b9[r];
        out[orow + r] = 1.0f / (1.0f + __expf(-v));
      }
    }
  }
}

extern "C" void kernel_launch(void* const* d_in, const int* in_sizes, int n_in,
                              void* d_out, int out_size, void* d_ws, size_t ws_size,
                              hipStream_t stream) {
  const float* x  = (const float*)d_in[0];
  const float* W1 = (const float*)d_in[1];  const float* b1 = (const float*)d_in[2];
  const float* W2 = (const float*)d_in[3];  const float* b2 = (const float*)d_in[4];
  const float* W3 = (const float*)d_in[5];  const float* b3 = (const float*)d_in[6];
  const float* W4 = (const float*)d_in[7];  const float* b4 = (const float*)d_in[8];
  const float* W5 = (const float*)d_in[9];  const float* b5 = (const float*)d_in[10];
  const float* W6 = (const float*)d_in[11]; const float* b6 = (const float*)d_in[12];
  const float* W7 = (const float*)d_in[13]; const float* b7 = (const float*)d_in[14];
  const float* W8 = (const float*)d_in[15]; const float* b8 = (const float*)d_in[16];
  const float* W9 = (const float*)d_in[17]; const float* b9 = (const float*)d_in[18];
  f16* wpk = (f16*)d_ws;

  repack_kernel<<<(TOTAL_FRAG_LANES + 255) / 256, 256, 0, stream>>>(
      W2, W3, W4, W5, W6, W7, W8, W9, wpk);

  mlp_kernel<<<1048576 / MT, 512, 0, stream>>>(
      x, W1, b1, wpk, b2, b3, b4, b5, b6, b7, b8, b9, (float*)d_out);
}